// Round 5
// baseline (125.269 us; speedup 1.0000x reference)
//
#include <hip/hip_runtime.h>
#include <math.h>

#define NBINS   10000     // N_NODES
#define NB      256       // edge-chunk blocks for hist/scatter
#define PSTRIDE 10016     // padded bin stride (u16 units, even -> u32-aligned rows)
#define HWORDS  5008      // packed LDS words (2 bins/word)
#define PER     10        // bins per thread in binscan (1024*10 >= 10000)
#define NSLICE  8         // edge slices per node in the gather

__device__ __forceinline__ unsigned short f2bf(float x) {
    unsigned int u = __float_as_uint(x);
    unsigned int r = (u + 0x7fffu + ((u >> 16) & 1u)) >> 16;   // rne
    return (unsigned short)r;
}
__device__ __forceinline__ float bf2f(unsigned short b) {
    return __uint_as_float(((unsigned int)b) << 16);
}

// ---------------------------------------------------------------------------
// K1: fused f32->bf16 feature conversion + per-block packed-u16 LDS histogram.
// ---------------------------------------------------------------------------
__global__ __launch_bounds__(256) void hist_convert_kernel(
        const int* __restrict__ dst, const float* __restrict__ feats,
        unsigned short* __restrict__ partial, unsigned short* __restrict__ feats_bf,
        int E, int chunk, int nf4) {
    const float4* f4 = (const float4*)feats;
    ushort4* b4 = (ushort4*)feats_bf;
    for (int i = blockIdx.x * blockDim.x + threadIdx.x; i < nf4;
         i += gridDim.x * blockDim.x) {
        float4 v = f4[i];
        ushort4 o;
        o.x = f2bf(v.x); o.y = f2bf(v.y); o.z = f2bf(v.z); o.w = f2bf(v.w);
        b4[i] = o;
    }
    __shared__ unsigned int h[HWORDS];
    for (int i = threadIdx.x; i < HWORDS; i += 256) h[i] = 0u;
    __syncthreads();
    int b = blockIdx.x;
    int start = b * chunk;
    int end   = min(start + chunk, E);
    for (int e = start + threadIdx.x; e < end; e += 256) {
        int d = dst[e];
        atomicAdd(&h[d >> 1], 1u << ((d & 1) * 16));
    }
    __syncthreads();
    unsigned int* row = (unsigned int*)(partial + (size_t)b * PSTRIDE);
    for (int i = threadIdx.x; i < HWORDS; i += 256) row[i] = h[i];
}

// ---------------------------------------------------------------------------
// K2a: per-bin exclusive scan across NB blocks (in place, u16), emit deg.
// 16-deep unroll: 16 outstanding loads per serial carry group.
// ---------------------------------------------------------------------------
__global__ __launch_bounds__(256) void colscan_kernel(unsigned short* __restrict__ partial,
                                                      int* __restrict__ deg, int nbins) {
    int bin = blockIdx.x * blockDim.x + threadIdx.x;
    if (bin >= nbins) return;
    int running = 0;
    for (int b = 0; b < NB; b += 16) {
        int v[16];
        #pragma unroll
        for (int k = 0; k < 16; k++)
            v[k] = partial[(size_t)(b + k) * PSTRIDE + bin];
        #pragma unroll
        for (int k = 0; k < 16; k++) {
            partial[(size_t)(b + k) * PSTRIDE + bin] = (unsigned short)running;
            running += v[k];
        }
    }
    deg[bin] = running;
}

// ---------------------------------------------------------------------------
// K2b: exclusive scan deg[0..n) -> offs[0..n]. One 1024-thread block.
// ---------------------------------------------------------------------------
__global__ __launch_bounds__(1024) void binscan_kernel(const int* __restrict__ deg,
                                                       int* __restrict__ offs, int n) {
    __shared__ int wsum[16];
    int tid  = threadIdx.x;
    int lane = tid & 63;
    int wave = tid >> 6;
    int base = tid * PER;
    int local[PER];
    int s = 0;
    #pragma unroll
    for (int i = 0; i < PER; i++) {
        int idx = base + i;
        int v = (idx < n) ? deg[idx] : 0;
        local[i] = s;
        s += v;
    }
    int incl = s;
    #pragma unroll
    for (int off = 1; off < 64; off <<= 1) {
        int t = __shfl_up(incl, off, 64);
        if (lane >= off) incl += t;
    }
    if (lane == 63) wsum[wave] = incl;
    __syncthreads();
    if (wave == 0) {
        int v = (lane < 16) ? wsum[lane] : 0;
        #pragma unroll
        for (int off = 1; off < 16; off <<= 1) {
            int t = __shfl_up(v, off, 64);
            if (lane >= off) v += t;
        }
        if (lane < 16) wsum[lane] = v;
    }
    __syncthreads();
    int wprefix = (wave > 0) ? wsum[wave - 1] : 0;
    int excl = wprefix + incl - s;
    #pragma unroll
    for (int i = 0; i < PER; i++) {
        int idx = base + i;
        if (idx < n) offs[idx] = excl + local[i];
    }
    if (tid == 1023) offs[n] = wprefix + incl;
}

// ---------------------------------------------------------------------------
// K3: scatter, zero global atomics; edge ids stored as u16.
// ---------------------------------------------------------------------------
__global__ __launch_bounds__(256) void scatter_kernel(const int* __restrict__ src,
                                                      const int* __restrict__ dst,
                                                      const int* __restrict__ offs,
                                                      const unsigned short* __restrict__ partial,
                                                      unsigned short* __restrict__ edge_src,
                                                      int E, int chunk) {
    __shared__ unsigned int h[HWORDS];
    for (int i = threadIdx.x; i < HWORDS; i += 256) h[i] = 0u;
    __syncthreads();
    int b = blockIdx.x;
    const unsigned short* base = partial + (size_t)b * PSTRIDE;
    int start = b * chunk;
    int end   = min(start + chunk, E);
    for (int e = start + threadIdx.x; e < end; e += 256) {
        int d = dst[e];
        unsigned int old = atomicAdd(&h[d >> 1], 1u << ((d & 1) * 16));
        int r = (int)((old >> ((d & 1) * 16)) & 0xffffu);
        edge_src[offs[d] + (int)base[d] + r] = (unsigned short)src[e];
    }
}

// ---------------------------------------------------------------------------
// K4a: sliced gather. Half-wave (32 lanes x ushort4 = one 256B bf16 row) per
// (node, slice); slice s covers edges start+s, start+s+8, ... (stride NSLICE).
// 80k half-waves -> 40k waves -> full occupancy; latency fully hidden.
// ---------------------------------------------------------------------------
__global__ __launch_bounds__(256) void gather_phaseA(
        const unsigned short* __restrict__ feats_bf, const int* __restrict__ offs,
        const unsigned short* __restrict__ edge_src, unsigned short* __restrict__ part,
        int n_nodes) {
    int gtid = blockIdx.x * blockDim.x + threadIdx.x;
    int hw   = gtid >> 5;            // half-wave id
    int col  = threadIdx.x & 31;     // ushort4 column
    int node = hw >> 3;              // NSLICE = 8
    int s    = hw & 7;
    if (node >= n_nodes) return;

    int start = offs[node];
    int end   = offs[node + 1];

    const ushort4* f4 = (const ushort4*)feats_bf;   // row stride = 32 ushort4
    float4 acc = make_float4(-INFINITY, -INFINITY, -INFINITY, -INFINITY);

    int j = start + s;
    for (; j + NSLICE < end; j += 2 * NSLICE) {
        int e0 = edge_src[j];
        int e1 = edge_src[j + NSLICE];
        ushort4 v0 = f4[(size_t)e0 * 32 + col];
        ushort4 v1 = f4[(size_t)e1 * 32 + col];
        acc.x = fmaxf(acc.x, fmaxf(bf2f(v0.x), bf2f(v1.x)));
        acc.y = fmaxf(acc.y, fmaxf(bf2f(v0.y), bf2f(v1.y)));
        acc.z = fmaxf(acc.z, fmaxf(bf2f(v0.z), bf2f(v1.z)));
        acc.w = fmaxf(acc.w, fmaxf(bf2f(v0.w), bf2f(v1.w)));
    }
    if (j < end) {
        int e0 = edge_src[j];
        ushort4 v0 = f4[(size_t)e0 * 32 + col];
        acc.x = fmaxf(acc.x, bf2f(v0.x));
        acc.y = fmaxf(acc.y, bf2f(v0.y));
        acc.z = fmaxf(acc.z, bf2f(v0.z));
        acc.w = fmaxf(acc.w, bf2f(v0.w));
    }

    // write bf16 partial (exact: values are bf16); empty slice -> -inf
    ushort4 o;
    o.x = f2bf(acc.x); o.y = f2bf(acc.y); o.z = f2bf(acc.z); o.w = f2bf(acc.w);
    ((ushort4*)part)[(size_t)hw * 32 + col] = o;
}

// ---------------------------------------------------------------------------
// K4b: combine 8 slice-partials per node, zero-fill empty nodes, write f32.
// ---------------------------------------------------------------------------
__global__ __launch_bounds__(256) void gather_phaseB(
        const unsigned short* __restrict__ part, const int* __restrict__ offs,
        float* __restrict__ out, int n_nodes) {
    int gtid = blockIdx.x * blockDim.x + threadIdx.x;
    int node = gtid >> 5;
    int col  = gtid & 31;
    if (node >= n_nodes) return;

    const ushort4* p4 = (const ushort4*)part;
    size_t base = (size_t)node * NSLICE * 32 + col;
    float4 acc = make_float4(-INFINITY, -INFINITY, -INFINITY, -INFINITY);
    #pragma unroll
    for (int s = 0; s < NSLICE; s++) {
        ushort4 v = p4[base + (size_t)s * 32];
        acc.x = fmaxf(acc.x, bf2f(v.x));
        acc.y = fmaxf(acc.y, bf2f(v.y));
        acc.z = fmaxf(acc.z, bf2f(v.z));
        acc.w = fmaxf(acc.w, bf2f(v.w));
    }
    if (offs[node] == offs[node + 1]) { acc.x = 0.f; acc.y = 0.f; acc.z = 0.f; acc.w = 0.f; }
    ((float4*)out)[(size_t)node * 32 + col] = acc;
}

// ---------------------------------------------------------------------------
extern "C" void kernel_launch(void* const* d_in, const int* in_sizes, int n_in,
                              void* d_out, int out_size, void* d_ws, size_t ws_size,
                              hipStream_t stream) {
    const float* feats = (const float*)d_in[0];
    const int*   src   = (const int*)d_in[1];
    const int*   dst   = (const int*)d_in[2];
    float*       out   = (float*)d_out;

    const int E = in_sizes[1];             // 640000
    const int N = NBINS;                   // 10000
    const int chunk = (E + NB - 1) / NB;   // 2500
    const int nf4   = (N * 128) / 4;       // 320000 float4s

    // workspace layout (~31 MB of 256 MiB ws)
    char* w = (char*)d_ws;
    unsigned short* partial  = (unsigned short*)w;                 // NB*PSTRIDE u16
    w += (size_t)NB * PSTRIDE * sizeof(unsigned short);
    int* deg  = (int*)w;  w += PSTRIDE * sizeof(int);
    int* offs = (int*)w;  w += PSTRIDE * sizeof(int);
    unsigned short* edge_src = (unsigned short*)w;
    w += (size_t)((E + 16) & ~15) * sizeof(unsigned short);
    unsigned short* feats_bf = (unsigned short*)w;                 // N*128 u16
    w += (size_t)N * 128 * sizeof(unsigned short);
    unsigned short* part = (unsigned short*)w;                     // N*NSLICE*128 u16 = 20.5 MB

    hist_convert_kernel<<<NB, 256, 0, stream>>>(dst, feats, partial, feats_bf, E, chunk, nf4);
    colscan_kernel<<<(N + 255) / 256, 256, 0, stream>>>(partial, deg, N);
    binscan_kernel<<<1, 1024, 0, stream>>>(deg, offs, N);
    scatter_kernel<<<NB, 256, 0, stream>>>(src, dst, offs, partial, edge_src, E, chunk);

    int hw_total = N * NSLICE;                       // 80000 half-waves
    int blocksA  = (hw_total * 32 + 255) / 256;      // 10000
    gather_phaseA<<<blocksA, 256, 0, stream>>>(feats_bf, offs, edge_src, part, N);

    int blocksB = (N * 32 + 255) / 256;              // 1250
    gather_phaseB<<<blocksB, 256, 0, stream>>>(part, offs, out, N);
}